// Round 8
// baseline (1270.562 us; speedup 1.0000x reference)
//
#include <hip/hip_runtime.h>
#include <stdint.h>

#define EPS 1e-5f
#define SLOPE 0.01f

typedef short bf16x8 __attribute__((ext_vector_type(8)));
typedef float f32x16 __attribute__((ext_vector_type(16)));

// round-to-nearest-even fp32 -> bf16
__device__ __forceinline__ uint16_t f2bf(float x) {
  union { float f; uint32_t u; } v; v.f = x;
  return (uint16_t)((v.u + 0x7fffu + ((v.u >> 16) & 1u)) >> 16);
}

// async global->LDS, 16B per lane; LDS dest = wave-uniform base + lane*16
__device__ __forceinline__ void g2lds16(const void* g, void* l) {
  __builtin_amdgcn_global_load_lds(
      (const __attribute__((address_space(1))) void*)g,
      (__attribute__((address_space(3))) void*)l, 16, 0, 0);
}

// ---------------------------------------------------------------------------
// prep: bn scale/bias folding.
// ---------------------------------------------------------------------------
__global__ void prep_bn(const float* g1, const float* b1, const float* m1, const float* v1,
                        const float* g2, const float* b2, const float* m2, const float* v2,
                        const float* g3, const float* b3, const float* m3, const float* v3,
                        const float* go, const float* bo, const float* mo, const float* vo,
                        const float* bo1,
                        float* s1, float* be1, float* s2, float* be2,
                        float* s3, float* be3, float* so, float* beo) {
  int t = threadIdx.x;
  if (t < 256) { float s = g1[t] / sqrtf(v1[t] + EPS); s1[t] = s; be1[t] = b1[t] - m1[t] * s; }
  if (t < 64)  { float s = g2[t] / sqrtf(v2[t] + EPS); s2[t] = s; be2[t] = b2[t] - m2[t] * s; }
  if (t < 32)  { float s = g3[t] / sqrtf(v3[t] + EPS); s3[t] = s; be3[t] = b3[t] - m3[t] * s; }
  if (t < 32)  { float s = go[t] / sqrtf(vo[t] + EPS); so[t] = s; beo[t] = bo[t] + (bo1[t] - mo[t]) * s; }
}

// ---------------------------------------------------------------------------
// weight transform: W[co][ci][27] fp32 -> Wt[t][co][ci] bf16
// ---------------------------------------------------------------------------
__global__ void wtrans(const float* __restrict__ W, uint16_t* __restrict__ Wt,
                       int CO, int CI) {
  int idx = blockIdx.x * 256 + threadIdx.x;
  int total = CO * CI * 27;
  if (idx >= total) return;
  int t = idx / (CO * CI);
  int rem = idx % (CO * CI);
  int co = rem / CI, ci = rem % CI;
  Wt[idx] = f2bf(W[((size_t)co * CI + ci) * 27 + t]);
}

// ---------------------------------------------------------------------------
// halo zero: padded buffer [NB][66][66][18][C] — zero d/h/w halo cells.
// ---------------------------------------------------------------------------
__global__ __launch_bounds__(256) void halo_zero(uint16_t* __restrict__ base, int C) {
  int dpad = blockIdx.x % 66;
  int bd = blockIdx.x / 66;
  uint16_t* slab = base + ((size_t)bd * 78408 + (size_t)dpad * 1188) * C;
  int t = threadIdx.x;
  int tc = t & 7;
  bool dHalo = (dpad == 0) | (dpad == 65);
  int n4 = C >> 6;
  for (int cell = t >> 3; cell < 1188; cell += 32) {
    int hp = cell / 18, wp = cell % 18;
    if (!(dHalo || hp == 0 || hp == 65 || wp == 0 || wp == 17)) continue;
    uint4* q = (uint4*)(slab + (size_t)cell * C + tc * (C >> 3));
    for (int i = 0; i < n4; ++i) q[i] = make_uint4(0, 0, 0, 0);
  }
}

// ---------------------------------------------------------------------------
// fea NCDHW fp32 -> pad0 NDHWC bf16, padded dims [66][66][18][256].
// ---------------------------------------------------------------------------
__global__ __launch_bounds__(256) void transpose_fea(const float* __restrict__ fea,
                                                     uint16_t* __restrict__ pad0) {
  int tid = threadIdx.x;
  int idx = blockIdx.x;
  int half = idx & 1;
  int q = (idx >> 1) & 3;
  int d = (idx >> 3) & 63;
  int b = idx >> 9;
  int s = q * 256 + tid;
  int h = s >> 4, w = s & 15;
  const float* src = fea + (size_t)(b * 256 + half * 128) * 65536 + (size_t)d * 1024 + s;
  uint16_t* dst = pad0 + ((size_t)b * 78408 +
                          (size_t)((d + 1) * 1188 + (h + 1) * 18 + (w + 1))) * 256 + half * 128;
#pragma unroll 4
  for (int c8 = 0; c8 < 16; ++c8) {
    uint16_t v[8];
#pragma unroll
    for (int j = 0; j < 8; ++j)
      v[j] = f2bf(src[(size_t)(c8 * 8 + j) * 65536]);
    *(uint4*)&dst[c8 * 8] = *(uint4*)v;
  }
}

// ---------------------------------------------------------------------------
// Implicit-GEMM 3x3x3 conv, mfma_f32_32x32x16_bf16.
//   A (activations): LDS, BK=64, kw-extended rows [w'0..17][mh][ci64],
//     staged once per (dh,kc) via global_load_lds, reused kw=0,1,2.
//     Swizzle: unit stored at u ^ (w'&7) ^ ((mh&1)<<2)  — the mh-parity term
//     makes 32x32 fragment reads 2-way (lanes l / l+16 differ in mh parity
//     -> +16 bank offset), 2-way is free [m136].
//   B (weights): NOT in LDS.  Fragments loaded straight from L2 into VGPRs
//     (weights are L2-resident in every XCD), double-buffered one k-chunk
//     ahead; chunk-0 issued before the A barrier so its latency hides under
//     the A-DMA drain.  No barriers between the 12 chunks of an epoch.
//   Barriers: 2 per (dh,kc) epoch (A reuse + A drain) — 72 total vs r3's 216.
//   MFMA 32x32x16 conventions (r7-verified): A row=lane&31, k=(lane>>5)*8+j;
//   C/D col=lane&31, row=(reg&3)+8*(reg>>2)+4*(lane>>5).
// ---------------------------------------------------------------------------
template <int CI, int CO, int MH, int WM, int WN, bool LAST>
__global__ __launch_bounds__(256, 2) void conv_mfma(const uint16_t* __restrict__ padIn,
                                                    const uint16_t* __restrict__ Wt,
                                                    const float* __restrict__ bnS,
                                                    const float* __restrict__ bnB,
                                                    uint16_t* __restrict__ padOut,
                                                    float* __restrict__ x3out) {
  constexpr int MTILE = MH * 16;
  constexpr int MPW = MTILE / WM;
  constexpr int NPW = CO / WN;
  constexpr int MT2 = MPW / 32;        // 32x32 m-tiles per wave
  constexpr int NT2 = NPW / 32;        // 32x32 n-tiles per wave
  constexpr int KC = CI / 64;
  constexpr int HB = 64 / MH;
  constexpr int AHI = MH / 8;          // A staging instrs per w'-slot
  constexpr int ROWSTR = 18 * CI;

  __shared__ __align__(16) uint16_t Alds[20 * MH * 64];  // [w'][mh][ci64]

  const int tid = threadIdx.x;
  const int lane = tid & 63;
  const int wv = tid >> 6;
  const int wvm = wv / WN;
  const int wvn = wv % WN;

  const int mt = blockIdx.x;
  const int b = mt / (64 * HB);
  const int r = mt % (64 * HB);
  const int d = r / HB;
  const int h0 = (r % HB) * MH;

  // per-lane B voffset (elements): n-row x CI + k-octet
  const int laneOffB = (lane & 31) * CI + (lane >> 5) * 8;
  // wave-uniform n base
  const int nBase = wvn * NPW;

  f32x16 acc[MT2][NT2] = {};

  const size_t bOffIn = (size_t)b * 78408 * CI;

  for (int dh = 0; dh < 9; ++dh) {
    const int kd = dh / 3, kh = dh % 3;
    const size_t Abase = bOffIn + (size_t)((d + kd) * 1188 + (h0 + kh) * 18) * CI;
    for (int kc = 0; kc < KC; ++kc) {
      bf16x8 bb[2][NT2];
      // prefetch B chunk 0 of this epoch (register loads — no LDS hazard;
      // latency hidden under A staging + barrier drain)
      {
        const uint16_t* bg = Wt + ((size_t)(dh * 3 + 0) * CO + nBase) * CI + kc * 64 + 0 * 16;
#pragma unroll
        for (int nt = 0; nt < NT2; ++nt)
          bb[0][nt] = *(const bf16x8*)(bg + nt * 32 * CI + laneOffB);
      }
      __syncthreads();  // previous epoch's A reads done
      {
        // stage A_ext: wave wv covers w'-slots wv*5..wv*5+4 (20 incl. dummies)
        // lanes: mh=lane>>3, unit=lane&7; stored unit = u^(wp&7)^((mh&1)<<2)
        const uint16_t* agBase = padIn + Abase + kc * 64 + (size_t)(lane >> 3) * ROWSTR;
#pragma unroll
        for (int p = 0; p < 5; ++p) {
          int wp = wv * 5 + p;
          int gu = (lane & 7) ^ (wp & 7) ^ (((lane >> 3) & 1) << 2);
#pragma unroll
          for (int hf = 0; hf < AHI; ++hf)
            g2lds16(agBase + (size_t)(hf * 8) * ROWSTR + wp * CI + gu * 8,
                    (char*)Alds + wp * (MH * 128) + hf * 1024);
        }
      }
      __syncthreads();  // A DMA drained (B chunk-0 loads drain here too — cheap)

      // 12 chunks: (kw 0..2) x (kch 0..3), K=16 each.  B prefetched 1 ahead.
#pragma unroll
      for (int c = 0; c < 12; ++c) {
        const int kw = c >> 2, kch = c & 3;
        if (c < 11) {
          const int nkw = (c + 1) >> 2, nkch = (c + 1) & 3;
          const uint16_t* bg = Wt + ((size_t)(dh * 3 + nkw) * CO + nBase) * CI +
                               kc * 64 + nkch * 16;
#pragma unroll
          for (int nt = 0; nt < NT2; ++nt)
            bb[(c + 1) & 1][nt] = *(const bf16x8*)(bg + nt * 32 * CI + laneOffB);
        }
        bf16x8 af[MT2];
#pragma unroll
        for (int mtI = 0; mtI < MT2; ++mtI) {
          int wq = (lane & 15) + kw;
          int mh = wvm * (MPW / 16) + mtI * 2 + ((lane >> 4) & 1);
          int u = (kch * 2 + (lane >> 5)) ^ (wq & 7) ^ ((mh & 1) << 2);
          af[mtI] = *(const bf16x8*)&Alds[wq * (MH * 64) + mh * 64 + u * 8];
        }
#pragma unroll
        for (int mtI = 0; mtI < MT2; ++mtI)
#pragma unroll
          for (int nt = 0; nt < NT2; ++nt)
            acc[mtI][nt] = __builtin_amdgcn_mfma_f32_32x32x16_bf16(
                af[mtI], bb[c & 1][nt], acc[mtI][nt], 0, 0, 0);
      }
    }
  }

  // epilogue: y = x*s + beta, LeakyReLU
  // C/D 32x32: col=lane&31, row=(reg&3)+8*(reg>>2)+4*(lane>>5)
  const int col = lane & 31;
  const int rbase = 4 * (lane >> 5);
#pragma unroll
  for (int nt = 0; nt < NT2; ++nt) {
    const int co = nBase + nt * 32 + col;
    const float sv = bnS[co];
    const float bv = bnB[co];
#pragma unroll
    for (int mtI = 0; mtI < MT2; ++mtI) {
#pragma unroll
      for (int reg = 0; reg < 16; ++reg) {
        int m = wvm * MPW + mtI * 32 + (reg & 3) + 8 * (reg >> 2) + rbase;
        float v = acc[mtI][nt][reg] * sv + bv;
        v = v > 0.f ? v : SLOPE * v;
        int mh = m >> 4, w = m & 15;
        if (!LAST) {
          size_t o = ((size_t)b * 78408 +
                      (size_t)((d + 1) * 1188 + (h0 + mh + 1) * 18 + (w + 1))) * CO + co;
          padOut[o] = f2bf(v);
        } else {
          size_t o = ((size_t)b * 65536 + (size_t)((d * 64 + h0 + mh) * 16 + w)) * 32 + co;
          x3out[o] = v;
        }
      }
    }
  }
}

// ---------------------------------------------------------------------------
// gather + point MLP, all fp32. One thread per point.
// ---------------------------------------------------------------------------
__global__ __launch_bounds__(256) void gather_mlp(const float* __restrict__ x3,
                                                  const int* __restrict__ gidx,
                                                  const float* __restrict__ xyz,
                                                  const float* __restrict__ Wo1,
                                                  const float* __restrict__ so,
                                                  const float* __restrict__ beo,
                                                  const float* __restrict__ Wo2,
                                                  const float* __restrict__ bo2,
                                                  float* __restrict__ out) {
  __shared__ __align__(16) float w1[35 * 32];
  __shared__ float w2[32 * 3];
  __shared__ float sS[32], sB[32], b2s[3];
  int tid = threadIdx.x;
  for (int i = tid; i < 1120; i += 256) w1[i] = Wo1[i];
  if (tid < 96) w2[tid] = Wo2[tid];
  if (tid < 32) { sS[tid] = so[tid]; sB[tid] = beo[tid]; }
  if (tid < 3) b2s[tid] = bo2[tid];
  __syncthreads();

  int idx = blockIdx.x * 256 + tid;
  if (idx >= 200000) return;
  int b = idx >= 100000 ? 1 : 0;
  int gb = idx * 3;
  int i0 = gidx[gb], i1 = gidx[gb + 1], i2 = gidx[gb + 2];
  const float* pt = x3 + ((size_t)b * 65536 + (size_t)((i0 * 64 + i1) * 16 + i2)) * 32;

  float h[35];
#pragma unroll
  for (int q = 0; q < 8; ++q) {
    float4 v = *(const float4*)(pt + q * 4);
    h[q * 4] = v.x; h[q * 4 + 1] = v.y; h[q * 4 + 2] = v.z; h[q * 4 + 3] = v.w;
  }
  h[32] = xyz[gb]; h[33] = xyz[gb + 1]; h[34] = xyz[gb + 2];

  float a[32];
#pragma unroll
  for (int j = 0; j < 32; ++j) a[j] = 0.f;
#pragma unroll
  for (int k = 0; k < 35; ++k) {
    float hk = h[k];
    const float4* wr = (const float4*)(w1 + k * 32);
#pragma unroll
    for (int q = 0; q < 8; ++q) {
      float4 wv = wr[q];
      a[q * 4 + 0] += hk * wv.x;
      a[q * 4 + 1] += hk * wv.y;
      a[q * 4 + 2] += hk * wv.z;
      a[q * 4 + 3] += hk * wv.w;
    }
  }
  float o0 = b2s[0], o1 = b2s[1], o2 = b2s[2];
#pragma unroll
  for (int j = 0; j < 32; ++j) {
    float y = a[j] * sS[j] + sB[j];
    y = y > 0.f ? y : 0.f;
    o0 += y * w2[j * 3 + 0];
    o1 += y * w2[j * 3 + 1];
    o2 += y * w2[j * 3 + 2];
  }
  out[gb] = o0; out[gb + 1] = o1; out[gb + 2] = o2;
}

// ---------------------------------------------------------------------------
// workspace layout: unchanged from r3.
// ---------------------------------------------------------------------------
extern "C" void kernel_launch(void* const* d_in, const int* in_sizes, int n_in,
                              void* d_out, int out_size, void* d_ws, size_t ws_size,
                              hipStream_t stream) {
  (void)in_sizes; (void)n_in; (void)out_size;
  if (ws_size < 165130000) return;

  const float* fea = (const float*)d_in[0];
  const int*   gidx = (const int*)d_in[1];
  const float* xyz = (const float*)d_in[2];
  const float* W1 = (const float*)d_in[3];
  const float* g1 = (const float*)d_in[4];
  const float* b1 = (const float*)d_in[5];
  const float* m1 = (const float*)d_in[6];
  const float* v1 = (const float*)d_in[7];
  const float* W2 = (const float*)d_in[8];
  const float* g2 = (const float*)d_in[9];
  const float* b2 = (const float*)d_in[10];
  const float* m2 = (const float*)d_in[11];
  const float* v2 = (const float*)d_in[12];
  const float* W3 = (const float*)d_in[13];
  const float* g3 = (const float*)d_in[14];
  const float* b3 = (const float*)d_in[15];
  const float* m3 = (const float*)d_in[16];
  const float* v3 = (const float*)d_in[17];
  const float* Wo1 = (const float*)d_in[18];
  const float* bo1 = (const float*)d_in[19];
  const float* go = (const float*)d_in[20];
  const float* bo = (const float*)d_in[21];
  const float* mo = (const float*)d_in[22];
  const float* vo = (const float*)d_in[23];
  const float* Wo2 = (const float*)d_in[24];
  const float* bo2 = (const float*)d_in[25];

  char* ws = (char*)d_ws;
  uint16_t* pad0 = (uint16_t*)(ws);
  uint16_t* pad1 = (uint16_t*)(ws + 80289792);
  uint16_t* Wt1 = (uint16_t*)(ws + 160579584);
  uint16_t* Wt2 = (uint16_t*)(ws + 164118528);
  uint16_t* Wt3 = (uint16_t*)(ws + 165003264);
  float* s1  = (float*)(ws + 165113856 + 0 * 1024);
  float* be1 = (float*)(ws + 165113856 + 1 * 1024);
  float* s2  = (float*)(ws + 165113856 + 2 * 1024);
  float* be2 = (float*)(ws + 165113856 + 3 * 1024);
  float* s3  = (float*)(ws + 165113856 + 4 * 1024);
  float* be3 = (float*)(ws + 165113856 + 5 * 1024);
  float* so  = (float*)(ws + 165113856 + 6 * 1024);
  float* beo = (float*)(ws + 165113856 + 7 * 1024);
  uint16_t* pad2 = (uint16_t*)(ws);
  float* x3 = (float*)(ws + 20072448);

  prep_bn<<<1, 256, 0, stream>>>(g1, b1, m1, v1, g2, b2, m2, v2, g3, b3, m3, v3,
                                 go, bo, mo, vo, bo1, s1, be1, s2, be2, s3, be3, so, beo);
  wtrans<<<6912, 256, 0, stream>>>(W1, Wt1, 256, 256);
  wtrans<<<1728, 256, 0, stream>>>(W2, Wt2, 64, 256);
  wtrans<<<216, 256, 0, stream>>>(W3, Wt3, 32, 64);
  halo_zero<<<264, 256, 0, stream>>>((uint16_t*)ws, 256);   // pad0+pad1 halos
  transpose_fea<<<1024, 256, 0, stream>>>(fea, pad0);

  // conv1: CI=256, CO=256, MH=8 (MTILE=128), WM=1 WN=4 -> per-wave 128x64
  conv_mfma<256, 256, 8, 1, 4, false>
      <<<1024, 256, 0, stream>>>(pad0, Wt1, s1, be1, pad1, nullptr);

  // pad2 halo (aliases pad0 region; pad0 dead after conv1 — stream-ordered)
  halo_zero<<<132, 256, 0, stream>>>((uint16_t*)ws, 64);

  // conv2: CI=256, CO=64, MH=16 (MTILE=256), WM=4 WN=1 -> per-wave 64x64
  conv_mfma<256, 64, 16, 4, 1, false>
      <<<512, 256, 0, stream>>>(pad1, Wt2, s2, be2, pad2, nullptr);

  // conv3: CI=64, CO=32, MH=16 (MTILE=256), WM=4 WN=1 -> per-wave 64x32
  conv_mfma<64, 32, 16, 4, 1, true>
      <<<512, 256, 0, stream>>>(pad2, Wt3, s3, be3, nullptr, x3);

  gather_mlp<<<782, 256, 0, stream>>>(x3, gidx, xyz, Wo1, so, beo, Wo2, bo2, (float*)d_out);
}

// Round 9
// 1182.238 us; speedup vs baseline: 1.0747x; 1.0747x over previous
//
#include <hip/hip_runtime.h>
#include <stdint.h>

#define EPS 1e-5f
#define SLOPE 0.01f

typedef short bf16x8 __attribute__((ext_vector_type(8)));
typedef float f32x16 __attribute__((ext_vector_type(16)));

// round-to-nearest-even fp32 -> bf16
__device__ __forceinline__ uint16_t f2bf(float x) {
  union { float f; uint32_t u; } v; v.f = x;
  return (uint16_t)((v.u + 0x7fffu + ((v.u >> 16) & 1u)) >> 16);
}

// async global->LDS, 16B per lane; LDS dest = wave-uniform base + lane*16
__device__ __forceinline__ void g2lds16(const void* g, void* l) {
  __builtin_amdgcn_global_load_lds(
      (const __attribute__((address_space(1))) void*)g,
      (__attribute__((address_space(3))) void*)l, 16, 0, 0);
}

// ---------------------------------------------------------------------------
// prep: bn scale/bias folding.
// ---------------------------------------------------------------------------
__global__ void prep_bn(const float* g1, const float* b1, const float* m1, const float* v1,
                        const float* g2, const float* b2, const float* m2, const float* v2,
                        const float* g3, const float* b3, const float* m3, const float* v3,
                        const float* go, const float* bo, const float* mo, const float* vo,
                        const float* bo1,
                        float* s1, float* be1, float* s2, float* be2,
                        float* s3, float* be3, float* so, float* beo) {
  int t = threadIdx.x;
  if (t < 256) { float s = g1[t] / sqrtf(v1[t] + EPS); s1[t] = s; be1[t] = b1[t] - m1[t] * s; }
  if (t < 64)  { float s = g2[t] / sqrtf(v2[t] + EPS); s2[t] = s; be2[t] = b2[t] - m2[t] * s; }
  if (t < 32)  { float s = g3[t] / sqrtf(v3[t] + EPS); s3[t] = s; be3[t] = b3[t] - m3[t] * s; }
  if (t < 32)  { float s = go[t] / sqrtf(vo[t] + EPS); so[t] = s; beo[t] = bo[t] + (bo1[t] - mo[t]) * s; }
}

// ---------------------------------------------------------------------------
// weight transform to FRAGMENT order:
// Wpk[chunk][co][16] bf16, chunk = ((dh*KC + kc)*3 + kw)*4 + kch,
// ci = kc*64 + kch*16 + j, tap = dh*3 + kw.  W is [CO][CI][27] fp32.
// A wave's B-fragment load (rows nt*32.., lane = row*32B + oct*16B) is then
// 1024B fully contiguous -> one coalesced VMEM request (the r8 scatter fix).
// ---------------------------------------------------------------------------
__global__ void wtrans(const float* __restrict__ W, uint16_t* __restrict__ Wt,
                       int CO, int CI, int KC) {
  int idx = blockIdx.x * 256 + threadIdx.x;
  int total = CO * CI * 27;
  if (idx >= total) return;
  int chunk = idx / (CO * 16);
  int rem = idx % (CO * 16);
  int co = rem / 16, j = rem % 16;
  int kch = chunk & 3, u = chunk >> 2;
  int kw = u % 3, v = u / 3;
  int kc = v % KC, dh = v / KC;
  int ci = kc * 64 + kch * 16 + j;
  int t = dh * 3 + kw;
  Wt[idx] = f2bf(W[((size_t)co * CI + ci) * 27 + t]);
}

// ---------------------------------------------------------------------------
// halo zero: padded buffer [NB][66][66][18][C] — zero d/h/w halo cells.
// ---------------------------------------------------------------------------
__global__ __launch_bounds__(256) void halo_zero(uint16_t* __restrict__ base, int C) {
  int dpad = blockIdx.x % 66;
  int bd = blockIdx.x / 66;
  uint16_t* slab = base + ((size_t)bd * 78408 + (size_t)dpad * 1188) * C;
  int t = threadIdx.x;
  int tc = t & 7;
  bool dHalo = (dpad == 0) | (dpad == 65);
  int n4 = C >> 6;
  for (int cell = t >> 3; cell < 1188; cell += 32) {
    int hp = cell / 18, wp = cell % 18;
    if (!(dHalo || hp == 0 || hp == 65 || wp == 0 || wp == 17)) continue;
    uint4* q = (uint4*)(slab + (size_t)cell * C + tc * (C >> 3));
    for (int i = 0; i < n4; ++i) q[i] = make_uint4(0, 0, 0, 0);
  }
}

// ---------------------------------------------------------------------------
// fea NCDHW fp32 -> pad0 NDHWC bf16, padded dims [66][66][18][256].
// ---------------------------------------------------------------------------
__global__ __launch_bounds__(256) void transpose_fea(const float* __restrict__ fea,
                                                     uint16_t* __restrict__ pad0) {
  int tid = threadIdx.x;
  int idx = blockIdx.x;
  int half = idx & 1;
  int q = (idx >> 1) & 3;
  int d = (idx >> 3) & 63;
  int b = idx >> 9;
  int s = q * 256 + tid;
  int h = s >> 4, w = s & 15;
  const float* src = fea + (size_t)(b * 256 + half * 128) * 65536 + (size_t)d * 1024 + s;
  uint16_t* dst = pad0 + ((size_t)b * 78408 +
                          (size_t)((d + 1) * 1188 + (h + 1) * 18 + (w + 1))) * 256 + half * 128;
#pragma unroll 4
  for (int c8 = 0; c8 < 16; ++c8) {
    uint16_t v[8];
#pragma unroll
    for (int j = 0; j < 8; ++j)
      v[j] = f2bf(src[(size_t)(c8 * 8 + j) * 65536]);
    *(uint4*)&dst[c8 * 8] = *(uint4*)v;
  }
}

// ---------------------------------------------------------------------------
// Implicit-GEMM 3x3x3 conv, mfma_f32_32x32x16_bf16.
//   A: LDS, BK=64, kw-extended rows [w'0..17][mh][ci64], staged once per
//     (dh,kc); swizzle u ^ (w'&7) ^ ((mh&1)<<2)  [r8: 0 conflicts].
//   B: registers, loaded from L2 via the fragment-ordered Wpk layout —
//     each load is 1024B contiguous (coalesced; fixes r8's 32-line scatter).
//     Double-buffered one k-chunk ahead; chunk-0 issued pre-barrier.
//   Barriers: 2 per (dh,kc) epoch.
//   MFMA 32x32x16 conventions (r7/r8-verified).
// ---------------------------------------------------------------------------
template <int CI, int CO, int MH, int WM, int WN, bool LAST>
__global__ __launch_bounds__(256, 2) void conv_mfma(const uint16_t* __restrict__ padIn,
                                                    const uint16_t* __restrict__ Wpk,
                                                    const float* __restrict__ bnS,
                                                    const float* __restrict__ bnB,
                                                    uint16_t* __restrict__ padOut,
                                                    float* __restrict__ x3out) {
  constexpr int MTILE = MH * 16;
  constexpr int MPW = MTILE / WM;
  constexpr int NPW = CO / WN;
  constexpr int MT2 = MPW / 32;        // 32x32 m-tiles per wave
  constexpr int NT2 = NPW / 32;        // 32x32 n-tiles per wave
  constexpr int KC = CI / 64;
  constexpr int HB = 64 / MH;
  constexpr int AHI = MH / 8;          // A staging instrs per w'-slot
  constexpr int ROWSTR = 18 * CI;

  __shared__ __align__(16) uint16_t Alds[20 * MH * 64];  // [w'][mh][ci64]

  const int tid = threadIdx.x;
  const int lane = tid & 63;
  const int wv = tid >> 6;
  const int wvm = wv / WN;
  const int wvn = wv % WN;

  const int mt = blockIdx.x;
  const int b = mt / (64 * HB);
  const int r = mt % (64 * HB);
  const int d = r / HB;
  const int h0 = (r % HB) * MH;

  // per-lane B offset within a chunk-tile (elements): row*16 + oct*8
  const int laneB = (lane & 31) * 16 + (lane >> 5) * 8;
  const int nBase = wvn * NPW;         // wave-uniform co base

  f32x16 acc[MT2][NT2] = {};

  const size_t bOffIn = (size_t)b * 78408 * CI;

  for (int dh = 0; dh < 9; ++dh) {
    const int kd = dh / 3, kh = dh % 3;
    const size_t Abase = bOffIn + (size_t)((d + kd) * 1188 + (h0 + kh) * 18) * CI;
    for (int kc = 0; kc < KC; ++kc) {
      // base chunk index of this epoch (12 chunks follow contiguously)
      const size_t ep0 = (size_t)((dh * KC + kc) * 12) * (CO * 16);
      bf16x8 bb[2][NT2];
      // prefetch B chunk 0 (coalesced 1KB per NT2-tile; drains under A DMA)
      {
        const uint16_t* bg = Wpk + ep0 + (size_t)nBase * 16 + laneB;
#pragma unroll
        for (int nt = 0; nt < NT2; ++nt)
          bb[0][nt] = *(const bf16x8*)(bg + nt * 512);
      }
      __syncthreads();  // previous epoch's A reads done
      {
        // stage A_ext: wave wv covers w'-slots wv*5..wv*5+4 (20 incl. dummies)
        const uint16_t* agBase = padIn + Abase + kc * 64 + (size_t)(lane >> 3) * ROWSTR;
#pragma unroll
        for (int p = 0; p < 5; ++p) {
          int wp = wv * 5 + p;
          int gu = (lane & 7) ^ (wp & 7) ^ (((lane >> 3) & 1) << 2);
#pragma unroll
          for (int hf = 0; hf < AHI; ++hf)
            g2lds16(agBase + (size_t)(hf * 8) * ROWSTR + wp * CI + gu * 8,
                    (char*)Alds + wp * (MH * 128) + hf * 1024);
        }
      }
      __syncthreads();  // A DMA drained

      // 12 chunks: (kw 0..2) x (kch 0..3), K=16 each; B prefetched 1 ahead.
#pragma unroll
      for (int c = 0; c < 12; ++c) {
        const int kw = c >> 2, kch = c & 3;
        if (c < 11) {
          const uint16_t* bg = Wpk + ep0 + (size_t)(c + 1) * (CO * 16) +
                               (size_t)nBase * 16 + laneB;
#pragma unroll
          for (int nt = 0; nt < NT2; ++nt)
            bb[(c + 1) & 1][nt] = *(const bf16x8*)(bg + nt * 512);
        }
        bf16x8 af[MT2];
#pragma unroll
        for (int mtI = 0; mtI < MT2; ++mtI) {
          int wq = (lane & 15) + kw;
          int mh = wvm * (MPW / 16) + mtI * 2 + ((lane >> 4) & 1);
          int u = (kch * 2 + (lane >> 5)) ^ (wq & 7) ^ ((mh & 1) << 2);
          af[mtI] = *(const bf16x8*)&Alds[wq * (MH * 64) + mh * 64 + u * 8];
        }
#pragma unroll
        for (int mtI = 0; mtI < MT2; ++mtI)
#pragma unroll
          for (int nt = 0; nt < NT2; ++nt)
            acc[mtI][nt] = __builtin_amdgcn_mfma_f32_32x32x16_bf16(
                af[mtI], bb[c & 1][nt], acc[mtI][nt], 0, 0, 0);
      }
    }
  }

  // epilogue: y = x*s + beta, LeakyReLU
  // C/D 32x32: col=lane&31, row=(reg&3)+8*(reg>>2)+4*(lane>>5)
  const int col = lane & 31;
  const int rbase = 4 * (lane >> 5);
#pragma unroll
  for (int nt = 0; nt < NT2; ++nt) {
    const int co = nBase + nt * 32 + col;
    const float sv = bnS[co];
    const float bv = bnB[co];
#pragma unroll
    for (int mtI = 0; mtI < MT2; ++mtI) {
#pragma unroll
      for (int reg = 0; reg < 16; ++reg) {
        int m = wvm * MPW + mtI * 32 + (reg & 3) + 8 * (reg >> 2) + rbase;
        float v = acc[mtI][nt][reg] * sv + bv;
        v = v > 0.f ? v : SLOPE * v;
        int mh = m >> 4, w = m & 15;
        if (!LAST) {
          size_t o = ((size_t)b * 78408 +
                      (size_t)((d + 1) * 1188 + (h0 + mh + 1) * 18 + (w + 1))) * CO + co;
          padOut[o] = f2bf(v);
        } else {
          size_t o = ((size_t)b * 65536 + (size_t)((d * 64 + h0 + mh) * 16 + w)) * 32 + co;
          x3out[o] = v;
        }
      }
    }
  }
}

// ---------------------------------------------------------------------------
// gather + point MLP, all fp32. One thread per point.
// ---------------------------------------------------------------------------
__global__ __launch_bounds__(256) void gather_mlp(const float* __restrict__ x3,
                                                  const int* __restrict__ gidx,
                                                  const float* __restrict__ xyz,
                                                  const float* __restrict__ Wo1,
                                                  const float* __restrict__ so,
                                                  const float* __restrict__ beo,
                                                  const float* __restrict__ Wo2,
                                                  const float* __restrict__ bo2,
                                                  float* __restrict__ out) {
  __shared__ __align__(16) float w1[35 * 32];
  __shared__ float w2[32 * 3];
  __shared__ float sS[32], sB[32], b2s[3];
  int tid = threadIdx.x;
  for (int i = tid; i < 1120; i += 256) w1[i] = Wo1[i];
  if (tid < 96) w2[tid] = Wo2[tid];
  if (tid < 32) { sS[tid] = so[tid]; sB[tid] = beo[tid]; }
  if (tid < 3) b2s[tid] = bo2[tid];
  __syncthreads();

  int idx = blockIdx.x * 256 + tid;
  if (idx >= 200000) return;
  int b = idx >= 100000 ? 1 : 0;
  int gb = idx * 3;
  int i0 = gidx[gb], i1 = gidx[gb + 1], i2 = gidx[gb + 2];
  const float* pt = x3 + ((size_t)b * 65536 + (size_t)((i0 * 64 + i1) * 16 + i2)) * 32;

  float h[35];
#pragma unroll
  for (int q = 0; q < 8; ++q) {
    float4 v = *(const float4*)(pt + q * 4);
    h[q * 4] = v.x; h[q * 4 + 1] = v.y; h[q * 4 + 2] = v.z; h[q * 4 + 3] = v.w;
  }
  h[32] = xyz[gb]; h[33] = xyz[gb + 1]; h[34] = xyz[gb + 2];

  float a[32];
#pragma unroll
  for (int j = 0; j < 32; ++j) a[j] = 0.f;
#pragma unroll
  for (int k = 0; k < 35; ++k) {
    float hk = h[k];
    const float4* wr = (const float4*)(w1 + k * 32);
#pragma unroll
    for (int q = 0; q < 8; ++q) {
      float4 wv = wr[q];
      a[q * 4 + 0] += hk * wv.x;
      a[q * 4 + 1] += hk * wv.y;
      a[q * 4 + 2] += hk * wv.z;
      a[q * 4 + 3] += hk * wv.w;
    }
  }
  float o0 = b2s[0], o1 = b2s[1], o2 = b2s[2];
#pragma unroll
  for (int j = 0; j < 32; ++j) {
    float y = a[j] * sS[j] + sB[j];
    y = y > 0.f ? y : 0.f;
    o0 += y * w2[j * 3 + 0];
    o1 += y * w2[j * 3 + 1];
    o2 += y * w2[j * 3 + 2];
  }
  out[gb] = o0; out[gb + 1] = o1; out[gb + 2] = o2;
}

// ---------------------------------------------------------------------------
// workspace layout: unchanged from r3.
// ---------------------------------------------------------------------------
extern "C" void kernel_launch(void* const* d_in, const int* in_sizes, int n_in,
                              void* d_out, int out_size, void* d_ws, size_t ws_size,
                              hipStream_t stream) {
  (void)in_sizes; (void)n_in; (void)out_size;
  if (ws_size < 165130000) return;

  const float* fea = (const float*)d_in[0];
  const int*   gidx = (const int*)d_in[1];
  const float* xyz = (const float*)d_in[2];
  const float* W1 = (const float*)d_in[3];
  const float* g1 = (const float*)d_in[4];
  const float* b1 = (const float*)d_in[5];
  const float* m1 = (const float*)d_in[6];
  const float* v1 = (const float*)d_in[7];
  const float* W2 = (const float*)d_in[8];
  const float* g2 = (const float*)d_in[9];
  const float* b2 = (const float*)d_in[10];
  const float* m2 = (const float*)d_in[11];
  const float* v2 = (const float*)d_in[12];
  const float* W3 = (const float*)d_in[13];
  const float* g3 = (const float*)d_in[14];
  const float* b3 = (const float*)d_in[15];
  const float* m3 = (const float*)d_in[16];
  const float* v3 = (const float*)d_in[17];
  const float* Wo1 = (const float*)d_in[18];
  const float* bo1 = (const float*)d_in[19];
  const float* go = (const float*)d_in[20];
  const float* bo = (const float*)d_in[21];
  const float* mo = (const float*)d_in[22];
  const float* vo = (const float*)d_in[23];
  const float* Wo2 = (const float*)d_in[24];
  const float* bo2 = (const float*)d_in[25];

  char* ws = (char*)d_ws;
  uint16_t* pad0 = (uint16_t*)(ws);
  uint16_t* pad1 = (uint16_t*)(ws + 80289792);
  uint16_t* Wt1 = (uint16_t*)(ws + 160579584);
  uint16_t* Wt2 = (uint16_t*)(ws + 164118528);
  uint16_t* Wt3 = (uint16_t*)(ws + 165003264);
  float* s1  = (float*)(ws + 165113856 + 0 * 1024);
  float* be1 = (float*)(ws + 165113856 + 1 * 1024);
  float* s2  = (float*)(ws + 165113856 + 2 * 1024);
  float* be2 = (float*)(ws + 165113856 + 3 * 1024);
  float* s3  = (float*)(ws + 165113856 + 4 * 1024);
  float* be3 = (float*)(ws + 165113856 + 5 * 1024);
  float* so  = (float*)(ws + 165113856 + 6 * 1024);
  float* beo = (float*)(ws + 165113856 + 7 * 1024);
  uint16_t* pad2 = (uint16_t*)(ws);
  float* x3 = (float*)(ws + 20072448);

  prep_bn<<<1, 256, 0, stream>>>(g1, b1, m1, v1, g2, b2, m2, v2, g3, b3, m3, v3,
                                 go, bo, mo, vo, bo1, s1, be1, s2, be2, s3, be3, so, beo);
  wtrans<<<6912, 256, 0, stream>>>(W1, Wt1, 256, 256, 4);
  wtrans<<<1728, 256, 0, stream>>>(W2, Wt2, 64, 256, 4);
  wtrans<<<216, 256, 0, stream>>>(W3, Wt3, 32, 64, 1);
  halo_zero<<<264, 256, 0, stream>>>((uint16_t*)ws, 256);   // pad0+pad1 halos
  transpose_fea<<<1024, 256, 0, stream>>>(fea, pad0);

  // conv1: CI=256, CO=256, MH=8 (MTILE=128), WM=1 WN=4 -> per-wave 128x64
  conv_mfma<256, 256, 8, 1, 4, false>
      <<<1024, 256, 0, stream>>>(pad0, Wt1, s1, be1, pad1, nullptr);

  // pad2 halo (aliases pad0 region; pad0 dead after conv1 — stream-ordered)
  halo_zero<<<132, 256, 0, stream>>>((uint16_t*)ws, 64);

  // conv2: CI=256, CO=64, MH=16 (MTILE=256), WM=4 WN=1 -> per-wave 64x64
  conv_mfma<256, 64, 16, 4, 1, false>
      <<<512, 256, 0, stream>>>(pad1, Wt2, s2, be2, pad2, nullptr);

  // conv3: CI=64, CO=32, MH=16 (MTILE=256), WM=4 WN=1 -> per-wave 64x32
  conv_mfma<64, 32, 16, 4, 1, true>
      <<<512, 256, 0, stream>>>(pad2, Wt3, s3, be3, nullptr, x3);

  gather_mlp<<<782, 256, 0, stream>>>(x3, gidx, xyz, Wo1, so, beo, Wo2, bo2, (float*)d_out);
}